// Round 3
// baseline (336.380 us; speedup 1.0000x reference)
//
#include <hip/hip_runtime.h>

typedef __attribute__((ext_vector_type(4))) float floatx4;
typedef __attribute__((ext_vector_type(8))) short short8;
typedef __attribute__((ext_vector_type(8))) unsigned short ushort8v;

__device__ __forceinline__ unsigned short f2bf(float f) {
  // round-to-nearest-even fp32 -> bf16 (inputs are finite)
  unsigned int u = __builtin_bit_cast(unsigned int, f);
  u += 0x7FFFu + ((u >> 16) & 1u);
  return (unsigned short)(u >> 16);
}

#define KTOT 784   // true K (28*28)
#define KP   800   // padded K (25 * 32); Bt zeros in [784,800)
#define N1   128   // hidden width
#define BM   128   // rows per block
#define BK   32    // K per MFMA step
#define LDH  132   // LDS stride (ushorts) for h / w2t: 128 + 4 pad

// ---------------------------------------------------------------------------
// Prep: W1eff[q][n] = sum_{di,dj} conv_w[di,dj] * w1[(r-di)*26 + (c-dj)][n]
// stored TRANSPOSED as Bt[n][k] bf16, k padded to 800 with zeros.
// ---------------------------------------------------------------------------
__global__ void prep_w1eff(const float* __restrict__ conv_w,
                           const float* __restrict__ w1,
                           unsigned short* __restrict__ Bt) {
  const int n = blockIdx.x;  // 0..127
  float cw[9];
#pragma unroll
  for (int i = 0; i < 9; ++i) cw[i] = conv_w[i];
  for (int q = threadIdx.x; q < KP; q += blockDim.x) {
    float acc = 0.f;
    if (q < KTOT) {
      const int r = q / 28, c = q % 28;
#pragma unroll
      for (int di = 0; di < 3; ++di) {
        const int i2 = r - di;
        if (i2 < 0 || i2 >= 26) continue;
#pragma unroll
        for (int dj = 0; dj < 3; ++dj) {
          const int j2 = c - dj;
          if (j2 < 0 || j2 >= 26) continue;
          acc += cw[di * 3 + dj] * w1[(i2 * 26 + j2) * N1 + n];
        }
      }
    }
    Bt[n * KP + q] = f2bf(acc);
  }
}

// ---------------------------------------------------------------------------
// Fused: out = relu(x @ W1eff + b1) @ w2 + b2
// Barrier-free, LDS-free K-loop: MFMA fragments loaded DIRECTLY from global
// (A: 2x float4 from x, converted in-register; B: bf16 ushort8 from Bt).
// Waves fully independent for all 25 K-steps; LDS only used in the epilogue
// (GEMM2 through sH). 2 blocks/CU, register-ping-pong prefetch depth 1.
// ---------------------------------------------------------------------------
__global__ __launch_bounds__(256, 2)
void fused_mlp(const float* __restrict__ x,
               const unsigned short* __restrict__ Bt,
               const float* __restrict__ b1,
               const float* __restrict__ w2,
               const float* __restrict__ b2,
               float* __restrict__ out) {
  __shared__ __align__(16) unsigned short sH[BM * LDH];    // 33792 B
  __shared__ __align__(16) unsigned short sW2t[16 * LDH];  //  4224 B
  __shared__ float sB1[N1];
  __shared__ float sB2[16];

  const int tid  = threadIdx.x;
  const int wave = tid >> 6;
  const int lane = tid & 63;
  const int wm = wave & 1;   // wave row (2x2 wave grid)
  const int wn = wave >> 1;  // wave col
  const int lr = lane & 15;  // row/col within 16x16 fragment
  const int lq = lane >> 4;  // quad index (k-group)

  const long row_base = (long)blockIdx.x * BM;

  // preload w2 (transposed, bf16, padded to 16 cols), b1, b2
  for (int i = tid; i < 16 * N1; i += 256) {
    const int n = i >> 7, k = i & 127;
    sW2t[n * LDH + k] = (n < 10) ? f2bf(w2[k * 10 + n]) : (unsigned short)0;
  }
  if (tid < N1) sB1[tid] = b1[tid];
  if (tid < 10) sB2[tid] = b2[tid];
  // (barrier deferred to epilogue — nothing reads these until after K-loop)

  // per-wave fragment base pointers (k0 added as small offset in-loop)
  const float* aptr[4];
  const unsigned short* bptr[4];
#pragma unroll
  for (int i = 0; i < 4; ++i) {
    aptr[i] = x + (row_base + wm * 64 + i * 16 + lr) * (long)KTOT + lq * 8;
    bptr[i] = Bt + (wn * 64 + i * 16 + lr) * KP + lq * 8;
  }

  floatx4 acc[4][4] = {};

  auto load_a = [&](floatx4* pa, int kt) {
    int k0 = kt * BK;
    // tail: lanes lq>=2 would read past row end (k>=784); Bt is zero there,
    // so values are don't-care — clamp inside the row.
    if (kt == 24 && lq >= 2) k0 = 736;
#pragma unroll
    for (int i = 0; i < 4; ++i) {
      pa[2 * i]     = *(const floatx4*)(aptr[i] + k0);
      pa[2 * i + 1] = *(const floatx4*)(aptr[i] + k0 + 4);
    }
  };
  auto load_b = [&](ushort8v* pb, int kt) {
    const int k0 = kt * BK;
#pragma unroll
    for (int i = 0; i < 4; ++i)
      pb[i] = *(const ushort8v*)(bptr[i] + k0);
  };
  auto compute = [&](const floatx4* pa, const ushort8v* pb) {
    short8 af[4], bfv[4];
#pragma unroll
    for (int i = 0; i < 4; ++i) {
      ushort8v u;
#pragma unroll
      for (int j = 0; j < 4; ++j) {
        u[j]     = f2bf(pa[2 * i][j]);
        u[4 + j] = f2bf(pa[2 * i + 1][j]);
      }
      af[i]  = __builtin_bit_cast(short8, u);
      bfv[i] = __builtin_bit_cast(short8, pb[i]);
    }
#pragma unroll
    for (int im = 0; im < 4; ++im)
#pragma unroll
      for (int in = 0; in < 4; ++in)
        acc[im][in] = __builtin_amdgcn_mfma_f32_16x16x32_bf16(
            af[im], bfv[in], acc[im][in], 0, 0, 0);
  };

  // barrier-free K-loop, register ping-pong prefetch
  floatx4 pa0[8], pa1[8];
  ushort8v pb0[4], pb1[4];
  load_a(pa0, 0);
  load_b(pb0, 0);
  for (int kt = 0; kt < 24; kt += 2) {
    load_a(pa1, kt + 1);
    load_b(pb1, kt + 1);
    compute(pa0, pb0);
    load_a(pa0, kt + 2);   // kt+2 reaches 24 (tail-clamped in load_a)
    load_b(pb0, kt + 2);
    compute(pa1, pb1);
  }
  compute(pa0, pb0);  // kt = 24

  __syncthreads();  // preload writes (sB1/sB2/sW2t) -> visible to all

  // h = relu(acc + b1) -> bf16 in sH[row][col]
  // C/D layout: col = lane&15, row = (lane>>4)*4 + reg
#pragma unroll
  for (int im = 0; im < 4; ++im) {
#pragma unroll
    for (int in = 0; in < 4; ++in) {
      const int col = wn * 64 + in * 16 + lr;
      const float bb = sB1[col];
#pragma unroll
      for (int r = 0; r < 4; ++r) {
        const int row = wm * 64 + im * 16 + lq * 4 + r;
        const float v = acc[im][in][r] + bb;
        sH[row * LDH + col] = f2bf(v > 0.f ? v : 0.f);
      }
    }
  }
  __syncthreads();

  // GEMM2: out = h @ w2 + b2. Wave handles rows [wave*32, wave*32+32).
  floatx4 o0 = {0.f, 0.f, 0.f, 0.f}, o1 = {0.f, 0.f, 0.f, 0.f};
  const int m0 = wave * 32;
#pragma unroll
  for (int kc = 0; kc < 4; ++kc) {
    const int kof = kc * 32 + lq * 8;
    const short8 wv = *(const short8*)&sW2t[lr * LDH + kof];
    const short8 a0 = *(const short8*)&sH[(m0 + lr) * LDH + kof];
    const short8 a1 = *(const short8*)&sH[(m0 + 16 + lr) * LDH + kof];
    o0 = __builtin_amdgcn_mfma_f32_16x16x32_bf16(a0, wv, o0, 0, 0, 0);
    o1 = __builtin_amdgcn_mfma_f32_16x16x32_bf16(a1, wv, o1, 0, 0, 0);
  }
  if (lr < 10) {
    const float bb = sB2[lr];
#pragma unroll
    for (int r = 0; r < 4; ++r) {
      const long row = row_base + m0 + lq * 4 + r;
      out[row * 10 + lr] = o0[r] + bb;
      out[(row + 16) * 10 + lr] = o1[r] + bb;
    }
  }
}

extern "C" void kernel_launch(void* const* d_in, const int* in_sizes, int n_in,
                              void* d_out, int out_size, void* d_ws, size_t ws_size,
                              hipStream_t stream) {
  const float* x      = (const float*)d_in[0];  // 65536 x 784
  const float* conv_w = (const float*)d_in[1];  // 3 x 3
  const float* w1     = (const float*)d_in[2];  // 676 x 128
  const float* b1     = (const float*)d_in[3];  // 128
  const float* w2     = (const float*)d_in[4];  // 128 x 10
  const float* b2     = (const float*)d_in[5];  // 10
  float* out = (float*)d_out;                   // 65536 x 10

  unsigned short* Bt = (unsigned short*)d_ws;   // 128 x 800 bf16 = 204800 B

  prep_w1eff<<<128, 256, 0, stream>>>(conv_w, w1, Bt);
  fused_mlp<<<65536 / BM, 256, 0, stream>>>(x, Bt, b1, w2, b2, out);
}

// Round 4
// 306.943 us; speedup vs baseline: 1.0959x; 1.0959x over previous
//
#include <hip/hip_runtime.h>

typedef __attribute__((ext_vector_type(4))) float floatx4;
typedef __attribute__((ext_vector_type(8))) short short8;
typedef __attribute__((ext_vector_type(8))) unsigned short ushort8v;

__device__ __forceinline__ unsigned short f2bf(float f) {
  // round-to-nearest-even fp32 -> bf16 (inputs are finite)
  unsigned int u = __builtin_bit_cast(unsigned int, f);
  u += 0x7FFFu + ((u >> 16) & 1u);
  return (unsigned short)(u >> 16);
}

#define KTOT 784   // true K (28*28)
#define KP   800   // padded K (25 * 32); Bt zeros in [784,800)
#define N1   128   // hidden width
#define BM   128   // rows per block
#define LDH  132   // LDS stride (ushorts) for h / w2t: 128 + 4 pad

// async global->LDS DMA, 16 B per lane; LDS dst = uniform base + lane*16
typedef const __attribute__((address_space(1))) unsigned int* gas_ptr;
typedef __attribute__((address_space(3))) unsigned int* las_ptr;
__device__ __forceinline__ void dma16(const float* g, float* l) {
  __builtin_amdgcn_global_load_lds((gas_ptr)g, (las_ptr)l, 16, 0, 0);
}

// ---------------------------------------------------------------------------
// Prep: W1eff[q][n] = sum_{di,dj} conv_w[di,dj] * w1[(r-di)*26 + (c-dj)][n]
// stored TRANSPOSED as Bt[n][k] bf16, k padded to 800 with zeros.
// ---------------------------------------------------------------------------
__global__ void prep_w1eff(const float* __restrict__ conv_w,
                           const float* __restrict__ w1,
                           unsigned short* __restrict__ Bt) {
  const int n = blockIdx.x;  // 0..127
  float cw[9];
#pragma unroll
  for (int i = 0; i < 9; ++i) cw[i] = conv_w[i];
  for (int q = threadIdx.x; q < KP; q += blockDim.x) {
    float acc = 0.f;
    if (q < KTOT) {
      const int r = q / 28, c = q % 28;
#pragma unroll
      for (int di = 0; di < 3; ++di) {
        const int i2 = r - di;
        if (i2 < 0 || i2 >= 26) continue;
#pragma unroll
        for (int dj = 0; dj < 3; ++dj) {
          const int j2 = c - dj;
          if (j2 < 0 || j2 >= 26) continue;
          acc += cw[di * 3 + dj] * w1[(i2 * 26 + j2) * N1 + n];
        }
      }
    }
    Bt[n * KP + q] = f2bf(acc);
  }
}

// ---------------------------------------------------------------------------
// Fused: out = relu(x @ W1eff + b1) @ w2 + b2
// 512 thr (8 waves: 4m x 2n), BM=128. A staged fp32 via global_load_lds DMA
// (chunk-xor-swizzled), double-buffered; B direct global->reg (L2-resident).
// Sync: inline-asm "s_waitcnt vmcnt(4); s_barrier" — current buffer's DMAs
// retired, rB loads stay in flight across the barrier. No staging VGPRs.
// ---------------------------------------------------------------------------
__global__ __launch_bounds__(512, 4)
void fused_mlp(const float* __restrict__ x,
               const unsigned short* __restrict__ Bt,
               const float* __restrict__ b1,
               const float* __restrict__ w2,
               const float* __restrict__ b2,
               float* __restrict__ out) {
  __shared__ __align__(16) unsigned char smem[38592];
  float* sAf = (float*)smem;                       // [2][128 rows][32 fp32] swizzled
  unsigned short* sH = (unsigned short*)smem;      // overlay: [128][LDH]
  unsigned short* sW2t = (unsigned short*)(smem + 33792);  // [16][LDH]
  float* sB1 = (float*)(smem + 38016);
  float* sB2 = (float*)(smem + 38528);

  const int tid  = threadIdx.x;
  const int wave = tid >> 6;   // 0..7
  const int lane = tid & 63;
  const int wm = wave >> 1;    // 0..3 -> 32-row slice
  const int wn = wave & 1;     // 0..1 -> 64-col slice
  const int lr = lane & 15;
  const int lq = lane >> 4;

  const long row_base = (long)blockIdx.x * BM;
  const float* xblk = x + row_base * KTOT;

  // preload w2 (transposed bf16, padded to 16 cols), b1, b2
  for (int i = tid; i < 16 * N1; i += 512) {
    const int n = i >> 7, k = i & 127;
    sW2t[n * LDH + k] = (n < 10) ? f2bf(w2[k * 10 + n]) : (unsigned short)0;
  }
  if (tid < N1) sB1[tid] = b1[tid];
  if (tid >= N1 && tid < N1 + 10) sB2[tid - N1] = b2[tid - N1];

  // --- DMA staging addresses (2 instrs/wave; instr i covers rows i*8..i*8+8)
  // LDS slot s = lane&7 receives global chunk cg = s ^ (r&6)  (r&7 == lane>>3)
  const int i0 = wave * 2, i1 = wave * 2 + 1;
  const int rsub = lane >> 3;                 // row within 8-row group
  const int cg = (lane & 7) ^ (rsub & 6);     // swizzled global chunk
  const int ceff = (cg < 4) ? cg : cg - 4;    // tail clamp (k>=784 -> B zero)
  const float* gA0 = xblk + (long)(i0 * 8 + rsub) * KTOT + cg * 4;
  const float* gA1 = xblk + (long)(i1 * 8 + rsub) * KTOT + cg * 4;
  const float* gT0 = xblk + (long)(i0 * 8 + rsub) * KTOT + 768 + ceff * 4;
  const float* gT1 = xblk + (long)(i1 * 8 + rsub) * KTOT + 768 + ceff * 4;

  // B fragment pointers: Bt[n][k], n = wn*64 + in*16 + lr, k = lq*8 + kt*32
  const unsigned short* bptr[4];
#pragma unroll
  for (int in = 0; in < 4; ++in)
    bptr[in] = Bt + (long)(wn * 64 + in * 16 + lr) * KP + lq * 8;

  floatx4 acc[2][4] = {};

  // prologue: DMA data kt=0 into buf 0
  dma16(gA0, sAf + i0 * 256);
  dma16(gA1, sAf + i1 * 256);

  for (int kt = 0; kt < 25; ++kt) {
    const int buf = kt & 1;
    // B loads for this step (stay in flight across the barrier)
    ushort8v rB[4];
#pragma unroll
    for (int in = 0; in < 4; ++in)
      rB[in] = *(const ushort8v*)(bptr[in] + kt * 32);
    // retire this buffer's 2 DMAs (issued last iter); keep 4 rB in flight
    asm volatile("s_waitcnt vmcnt(4)\n\ts_barrier" ::: "memory");
    // prefetch next K-step into the other buffer (safe: post-barrier)
    {
      const int d = (kt + 1 <= 24) ? kt + 1 : 24;  // kt=24: redundant reload
      const float* g0 = (d < 24) ? gA0 + d * 32 : gT0;
      const float* g1 = (d < 24) ? gA1 + d * 32 : gT1;
      float* ldst = sAf + (buf ^ 1) * 4096;
      dma16(g0, ldst + i0 * 256);
      dma16(g1, ldst + i1 * 256);
    }
    // compute: A frags from LDS (fp32, swizzled) -> cvt bf16 -> MFMA
    const float* A = sAf + buf * 4096;
    short8 af[2];
#pragma unroll
    for (int im = 0; im < 2; ++im) {
      const int r = wm * 32 + im * 16 + lr;
      const int s0 = (2 * lq) ^ (r & 6);        // even; chunks s0, s0+1
      const floatx4* p = (const floatx4*)(A + r * 32 + s0 * 4);
      const floatx4 q0 = p[0], q1 = p[1];
      ushort8v u;
#pragma unroll
      for (int j = 0; j < 4; ++j) { u[j] = f2bf(q0[j]); u[4 + j] = f2bf(q1[j]); }
      af[im] = __builtin_bit_cast(short8, u);
    }
#pragma unroll
    for (int im = 0; im < 2; ++im)
#pragma unroll
      for (int in = 0; in < 4; ++in)
        acc[im][in] = __builtin_amdgcn_mfma_f32_16x16x32_bf16(
            af[im], __builtin_bit_cast(short8, rB[in]), acc[im][in], 0, 0, 0);
  }

  __syncthreads();  // drain all DMAs + finish LDS reads before sH overlay

  // h = relu(acc + b1) -> bf16 sH[row][col]; C/D: col=lane&15, row=lq*4+reg
#pragma unroll
  for (int im = 0; im < 2; ++im) {
#pragma unroll
    for (int in = 0; in < 4; ++in) {
      const int col = wn * 64 + in * 16 + lr;
      const float bb = sB1[col];
#pragma unroll
      for (int r = 0; r < 4; ++r) {
        const int row = wm * 32 + im * 16 + lq * 4 + r;
        const float v = acc[im][in][r] + bb;
        sH[row * LDH + col] = f2bf(v > 0.f ? v : 0.f);
      }
    }
  }
  __syncthreads();

  // GEMM2: out = h @ w2 + b2. Wave handles rows [wave*16, wave*16+16).
  floatx4 o = {0.f, 0.f, 0.f, 0.f};
  const int m0 = wave * 16;
#pragma unroll
  for (int kc = 0; kc < 4; ++kc) {
    const int kof = kc * 32 + lq * 8;
    const short8 wv = *(const short8*)&sW2t[lr * LDH + kof];
    const short8 a0 = *(const short8*)&sH[(m0 + lr) * LDH + kof];
    o = __builtin_amdgcn_mfma_f32_16x16x32_bf16(a0, wv, o, 0, 0, 0);
  }
  if (lr < 10) {
    const float bb = sB2[lr];
#pragma unroll
    for (int r = 0; r < 4; ++r) {
      const long row = row_base + m0 + lq * 4 + r;
      out[row * 10 + lr] = o[r] + bb;
    }
  }
}

extern "C" void kernel_launch(void* const* d_in, const int* in_sizes, int n_in,
                              void* d_out, int out_size, void* d_ws, size_t ws_size,
                              hipStream_t stream) {
  const float* x      = (const float*)d_in[0];  // 65536 x 784
  const float* conv_w = (const float*)d_in[1];  // 3 x 3
  const float* w1     = (const float*)d_in[2];  // 676 x 128
  const float* b1     = (const float*)d_in[3];  // 128
  const float* w2     = (const float*)d_in[4];  // 128 x 10
  const float* b2     = (const float*)d_in[5];  // 10
  float* out = (float*)d_out;                   // 65536 x 10

  unsigned short* Bt = (unsigned short*)d_ws;   // 128 x 800 bf16 = 204800 B

  prep_w1eff<<<128, 256, 0, stream>>>(conv_w, w1, Bt);
  fused_mlp<<<65536 / BM, 512, 0, stream>>>(x, Bt, b1, w2, b2, out);
}